// Round 1
// 96.607 us; speedup vs baseline: 1.0022x; 1.0022x over previous
//
#include <hip/hip_runtime.h>

// Problem constants
#define Bn     8
#define Cn     64
#define Hn     96
#define Wn     96
#define HW     9216        // Hn*Wn
#define K2     9
#define COUTn  64
#define KDIM   576         // Cn*K2
#define NT     256
#define RECS   64          // f16 per HWC pixel record (128 B)
#define XH_HALFS ((size_t)Bn*HW*RECS)
#define XH_BYTES (XH_HALFS*2)              // 9,437,184
// Tile geometry: 16 wide x 4 tall = 64 pixels/block
#define TW     16
#define TH     4
#define TILES_X 6
#define BLKS_PER_IMG 144   // (96/16)*(96/4)
#define BLK_PIX 64
// LDS window: 22 cols x 10 rows of 128B f16 records, chunk-XOR-swizzled
// (record rec, 16B chunk k stored at slot k ^ (rec&7); no padding needed).
#define WW     22
#define WH     10
#define WRECS  220                 // WW*WH
#define WCHUNKS 1760               // WRECS*8 16B chunks
#define WIN_ALLOC 28672            // 1792 chunks (32-chunk pad for tail DMA)
// Per-corner LDS base offset (q-XOR applied at read time): r*128 + (r&7)*16
#define BOFF(r) ((((r) << 3) | ((r) & 7)) << 4)

typedef __attribute__((ext_vector_type(8))) _Float16 half8;    // 16 B = 4 VGPR
typedef __attribute__((ext_vector_type(4))) _Float16 half4v;   // 8 B
typedef __attribute__((ext_vector_type(4))) float    float4v;  // MFMA acc

// ---- Fused pre-pass: x NCHW f32 -> HWC f16 global; weight -> f16 frag-major ----
// wfrag layout (kk-major for L1 locality): [kk(9)][mt(4)][ch(2)][lane(64)][j(8)]
// element: m=lane&15, q=lane>>4; cout=mt*16+m; c=ch*32+q*8+j.
__global__ __launch_bounds__(NT)
void prep_all(const float* __restrict__ x, _Float16* __restrict__ xh,
              const float* __restrict__ w, _Float16* __restrict__ wfrag) {
    const int blk = blockIdx.x;
    if (blk >= Bn * BLKS_PER_IMG) {
        int i = (blk - Bn * BLKS_PER_IMG) * NT + threadIdx.x;
        if (i < COUTn * KDIM) {
            int j    = i & 7;
            int lane = (i >> 3) & 63;
            int ch   = (i >> 9) & 1;
            int mt   = (i >> 10) & 3;
            int kk   = i >> 12;
            int m = lane & 15, q = lane >> 4;
            int cout = mt * 16 + m;
            int c    = ch * 32 + q * 8 + j;
            wfrag[i] = (_Float16)w[cout * KDIM + c * K2 + kk];
        }
        return;
    }
    __shared__ float tile[Cn * 65];     // 16.6 KB
    const int t    = threadIdx.x;
    const int lane = t & 63, wv = t >> 6;
    const int b    = blk & 7;
    const int pix0 = (blk >> 3) * BLK_PIX;   // linear 64-pixel groups

    #pragma unroll
    for (int i = 0; i < 16; ++i) {
        int c = wv + i * 4;
        tile[c * 65 + lane] = x[((size_t)b * Cn + c) * HW + pix0 + lane];
    }
    __syncthreads();
    #pragma unroll
    for (int pass = 0; pass < 4; ++pass) {
        int px = wv * 16 + pass * 4 + (lane >> 4);
        int c4 = (lane & 15) * 4;
        half4v v;
        v[0] = (_Float16)tile[(c4 + 0) * 65 + px];
        v[1] = (_Float16)tile[(c4 + 1) * 65 + px];
        v[2] = (_Float16)tile[(c4 + 2) * 65 + px];
        v[3] = (_Float16)tile[(c4 + 3) * 65 + px];
        *(half4v*)&xh[((size_t)b * HW + pix0 + px) * RECS + c4] = v;
    }
}

// ---- Main kernel ----
// LDS 37.9 KB -> 4 blocks/CU (was 49.5 KB / 3 blocks): occupancy 3->4 waves/SIMD.
// Window staged via global_load_lds DMA (linear dest, pre-swizzled source).
__global__ __launch_bounds__(NT, 4)
void deform_conv_win(const float* __restrict__ x,          // NCHW f32 (fallback only)
                     const _Float16* __restrict__ xh,      // HWC f16
                     const float* __restrict__ offset,
                     const _Float16* __restrict__ wfrag,
                     float* __restrict__ out) {
    __shared__ __align__(16) char smem[WIN_ALLOC];  // 28 KB window; epilogue sC aliases
    __shared__ int2   sB [K2 * BLK_PIX];   // 4.5 KB: 4 packed corner base-offsets + ok
    __shared__ half4v sWh[K2 * BLK_PIX];   // 4.5 KB bilinear weights (f16)

    const int tid  = threadIdx.x;
    const int b    = blockIdx.x & 7;                 // XCD swizzle
    const int tl   = blockIdx.x >> 3;
    const int ty0  = (tl / TILES_X) * TH;
    const int tx0  = (tl % TILES_X) * TW;
    const int wy0  = min(max(ty0 - 3, 0), Hn - WH);  // window origin (in-image)
    const int wx0  = min(max(tx0 - 3, 0), Wn - WW);

    const float* xb   = x + (size_t)b * (Cn * HW);
    const float* offb = offset + (size_t)b * (2 * K2 * HW);

    const int lane = tid & 63;
    const int wv   = tid >> 6;

    // ---- Phase 0a: sampling metadata per (kk, pixel) ----
    for (int e = tid; e < K2 * BLK_PIX; e += NT) {
        int kk = e >> 6;
        int pl = e & 63;
        int h = ty0 + (pl >> 4);
        int w = tx0 + (pl & 15);
        int pix = h * 96 + w;
        float offy = offb[(2 * kk) * HW + pix];
        float offx = offb[(2 * kk + 1) * HW + pix];
        float py = (float)(h - 1 + kk / 3) + offy;
        float px = (float)(w - 1 + kk % 3) + offx;
        float y0f = floorf(py), x0f = floorf(px);
        float ly = py - y0f, lx = px - x0f;
        int y0 = (int)y0f, x0 = (int)x0f;
        float vy0 = ((unsigned)y0 < 96u) ? 1.f : 0.f;
        float vy1 = ((unsigned)(y0 + 1) < 96u) ? 1.f : 0.f;
        float vx0 = ((unsigned)x0 < 96u) ? 1.f : 0.f;
        float vx1 = ((unsigned)(x0 + 1) < 96u) ? 1.f : 0.f;
        float w00 = (1.f - ly) * (1.f - lx) * vy0 * vx0;
        float w01 = (1.f - ly) * lx         * vy0 * vx1;
        float w10 = ly * (1.f - lx)         * vy1 * vx0;
        float w11 = ly * lx                 * vy1 * vx1;
        int y0c = min(max(y0, 0), 95);
        int x0c = min(max(x0, 0), 95);
        int dx = min(max(x0 + 1, 0), 95) - x0c;   // 0 or 1
        int dy = min(max(y0 + 1, 0), 95) - y0c;   // 0 or 1
        int ok = (y0c >= wy0) & (y0c + dy <= wy0 + WH - 1) &
                 (x0c >= wx0) & (x0c + dx <= wx0 + WW - 1);
        int r00 = (y0c - wy0) * WW + (x0c - wx0);
        int r01 = r00 + dx;
        int r10 = r00 + dy * WW;
        int r11 = r10 + dx;
        int2 pb;
        pb.x = ok ? (BOFF(r00) | 0x8000 | (BOFF(r01) << 16)) : 0;
        pb.y = ok ? (BOFF(r10) | (BOFF(r11) << 16)) : 0;
        sB[e] = pb;
        half4v hvv;
        hvv[0] = (_Float16)w00; hvv[1] = (_Float16)w01;
        hvv[2] = (_Float16)w10; hvv[3] = (_Float16)w11;
        sWh[e] = hvv;
    }

    // ---- Phase 0b: stage 22x10 window via global_load_lds DMA ----
    // Dest is linear per chunk c; source chunk pre-swizzled: w16 = (c&7)^((c>>3)&7)
    // so that a read of data-chunk k of record rec lands at slot k^(rec&7).
    {
        const _Float16* src = xh + ((size_t)b * HW + wy0 * 96 + wx0) * RECS;
        const int wvbase = wv << 6;
        #pragma unroll
        for (int i = 0; i < 7; ++i) {
            int c0 = i * NT + wvbase;          // wave-uniform chunk base
            int c  = c0 + lane;
            int cc = min(c, WCHUNKS - 1);      // tail lanes duplicate into pad
            int rec = cc >> 3;
            int w16 = (cc & 7) ^ (rec & 7);    // swizzled source chunk
            int row = rec / WW;
            int col = rec - row * WW;
            const _Float16* g = src + ((size_t)(row * 96 + col)) * RECS + w16 * 8;
            __builtin_amdgcn_global_load_lds(
                (const __attribute__((address_space(1))) unsigned int*)g,
                (__attribute__((address_space(3))) unsigned int*)(smem + (size_t)c0 * 16),
                16, 0, 0);
        }
    }
    __syncthreads();

    const int q    = lane >> 4;          // quad 0..3
    const int r    = lane & 15;          // 0..15
    const int plw  = wv * 16 + r;        // B-column pixel (local)
    const int qsh  = q << 4;             // XOR into swizzled chunk slot

    float4v acc0 = {0.f,0.f,0.f,0.f};
    float4v acc1 = {0.f,0.f,0.f,0.f};
    float4v acc2 = {0.f,0.f,0.f,0.f};
    float4v acc3 = {0.f,0.f,0.f,0.f};

    const _Float16* wlane = wfrag + lane * 8;

    for (int kk = 0; kk < 9; ++kk) {
        const int idx = kk * BLK_PIX + plw;
        const int2 pb = sB[idx];
        const half4v hv = sWh[idx];
        const _Float16 w0 = hv[0], w1 = hv[1], w2 = hv[2], w3 = hv[3];

        half8 bq0, bq1;
        if (pb.x & 0x8000) {
            // LDS window path (always taken for this data); packed v_pk_fma_f16.
            // Corner offsets: precomputed base ^ (q<<4); +64B chunk = offset ^ 64.
            const unsigned bx = (unsigned)pb.x, by = (unsigned)pb.y;
            const int o00 = (int)(bx & 0x7FFFu) ^ qsh;
            const int o01 = (int)(bx >> 16)     ^ qsh;
            const int o10 = (int)(by & 0xFFFFu) ^ qsh;
            const int o11 = (int)(by >> 16)     ^ qsh;
            half8 s00a = *(const half8*)(smem + o00);
            half8 s01a = *(const half8*)(smem + o01);
            half8 s10a = *(const half8*)(smem + o10);
            half8 s11a = *(const half8*)(smem + o11);
            half8 s00b = *(const half8*)(smem + (o00 ^ 64));
            half8 s01b = *(const half8*)(smem + (o01 ^ 64));
            half8 s10b = *(const half8*)(smem + (o10 ^ 64));
            half8 s11b = *(const half8*)(smem + (o11 ^ 64));
            bq0 = s00a * w0 + s01a * w1 + s10a * w2 + s11a * w3;
            bq1 = s00b * w0 + s01b * w1 + s10b * w2 + s11b * w3;
        } else {
            // Global f32 fallback (offset magnitude >= ~2; ~1e-4 of samples).
            // Recompute coords from scratch (no metadata table for this path).
            int h = ty0 + (plw >> 4);
            int w = tx0 + (plw & 15);
            int pix = h * 96 + w;
            float offy = offb[(2 * kk) * HW + pix];
            float offx = offb[(2 * kk + 1) * HW + pix];
            float py = (float)(h - 1 + kk / 3) + offy;
            float px = (float)(w - 1 + kk % 3) + offx;
            int y0 = (int)floorf(py), x0 = (int)floorf(px);
            int y0c = min(max(y0, 0), 95), x0c = min(max(x0, 0), 95);
            int dxv = min(max(x0 + 1, 0), 95) - x0c;
            int dyr = (min(max(y0 + 1, 0), 95) - y0c) * 96;
            int a00p = y0c * 96 + x0c;
            const float f0 = (float)w0, f1 = (float)w1, f2 = (float)w2, f3 = (float)w3;
            #pragma unroll
            for (int ch = 0; ch < 2; ++ch) {
                #pragma unroll
                for (int j = 0; j < 8; ++j) {
                    int c = ch * 32 + q * 8 + j;
                    const float* xc = xb + (size_t)c * HW + a00p;
                    float v = fmaf(f0, xc[0],
                              fmaf(f1, xc[dxv],
                              fmaf(f2, xc[dyr],
                                   f3 * xc[dyr + dxv])));
                    if (ch) bq1[j] = (_Float16)v; else bq0[j] = (_Float16)v;
                }
            }
        }

        // A fragments: dense 1024B wave-loads; kk-major layout -> 8KB/kk slab
        const _Float16* wkc = wlane + kk * 4096;
        half8 a00 = *(const half8*)(wkc + 0);
        half8 a10 = *(const half8*)(wkc + 1024);
        half8 a20 = *(const half8*)(wkc + 2048);
        half8 a30 = *(const half8*)(wkc + 3072);
        acc0 = __builtin_amdgcn_mfma_f32_16x16x32_f16(a00, bq0, acc0, 0, 0, 0);
        acc1 = __builtin_amdgcn_mfma_f32_16x16x32_f16(a10, bq0, acc1, 0, 0, 0);
        acc2 = __builtin_amdgcn_mfma_f32_16x16x32_f16(a20, bq0, acc2, 0, 0, 0);
        acc3 = __builtin_amdgcn_mfma_f32_16x16x32_f16(a30, bq0, acc3, 0, 0, 0);
        half8 a01 = *(const half8*)(wkc + 512);
        half8 a11 = *(const half8*)(wkc + 1536);
        half8 a21 = *(const half8*)(wkc + 2560);
        half8 a31 = *(const half8*)(wkc + 3584);
        acc0 = __builtin_amdgcn_mfma_f32_16x16x32_f16(a01, bq1, acc0, 0, 0, 0);
        acc1 = __builtin_amdgcn_mfma_f32_16x16x32_f16(a11, bq1, acc1, 0, 0, 0);
        acc2 = __builtin_amdgcn_mfma_f32_16x16x32_f16(a21, bq1, acc2, 0, 0, 0);
        acc3 = __builtin_amdgcn_mfma_f32_16x16x32_f16(a31, bq1, acc3, 0, 0, 0);
    }

    // ---- Epilogue: stage through LDS (aliases window) for dense stores ----
    __syncthreads();                       // all window reads done; reuse smem
    float* sC = (float*)smem;              // [64][68] floats = 17.4 KB <= 28 KB
    #pragma unroll
    for (int mt = 0; mt < 4; ++mt) {
        float4v a = (mt == 0) ? acc0 : (mt == 1) ? acc1 : (mt == 2) ? acc2 : acc3;
        int cout = mt * 16 + q * 4;
        #pragma unroll
        for (int reg = 0; reg < 4; ++reg)
            sC[(cout + reg) * 68 + plw] = a[reg];
    }
    __syncthreads();

    #pragma unroll
    for (int i = 0; i < 4; ++i) {
        int idx  = i * NT + tid;
        int cout = idx >> 4;
        int px4  = (idx & 15) * 4;         // local pixel 0..60
        int row  = px4 >> 4;
        int col  = px4 & 15;
        float4 v = *(const float4*)&sC[cout * 68 + px4];
        *(float4*)&out[((size_t)(b * COUTn + cout)) * HW + (ty0 + row) * 96 + tx0 + col] = v;
    }
}

extern "C" void kernel_launch(void* const* d_in, const int* in_sizes, int n_in,
                              void* d_out, int out_size, void* d_ws, size_t ws_size,
                              hipStream_t stream) {
    const float* x      = (const float*)d_in[0];
    const float* offset = (const float*)d_in[1];
    const float* weight = (const float*)d_in[2];
    float* out = (float*)d_out;

    _Float16* xh    = (_Float16*)d_ws;                          // 9,437,184 B
    _Float16* wfrag = (_Float16*)((char*)d_ws + XH_BYTES);      // 73,728 B

    prep_all<<<dim3(Bn * BLKS_PER_IMG + 144), dim3(NT), 0, stream>>>(x, xh, weight, wfrag);
    deform_conv_win<<<dim3(Bn * BLKS_PER_IMG), dim3(NT), 0, stream>>>(x, xh, offset, wfrag, out);
}